// Round 1
// baseline (70.077 us; speedup 1.0000x reference)
//
#include <hip/hip_runtime.h>

// QuadraticTimeVaryingVF via MFMA, prep + main (R8).
// out[n,h] = b[h] + sum_i o_i*(wlin[h,i] + sum_{j>=i} wq[h,i,j]*o_j)
//
// R7 post-mortem: main ~16us vs ~2.8us BW roofline (17.6MB) -> latency/
// issue-bound. ~190 of ~310 instrs/thread were per-h weight expansion
// (9 scattered loads + LDS zero + sqrt-triangle scatter + extra barrier),
// redone 16x redundantly per h across path-tiles, on the critical path.
// R8: 64-block prep kernel expands weights once per h into dense bf16
// [64][LSTR] rows (+ fp32 wlin) in d_ws (bit-identical scatter math).
// Main then stages W via 2.25 coalesced short8 loads, ONE barrier,
// MFMA + epilogue. Arithmetic bit-identical to R7.

#define DOBS 64
#define NH   64
#define WROW 2145
#define NQUAD 2080            // upper-tri count
#define LSTR 72               // LDS/dense row stride (bf16): 144 B, 16B-aligned
                              // (b128 reads at LSTR=72 sit at the 8-touch/bank
                              //  floor -> conflict-free)

typedef unsigned short u16;
typedef __attribute__((ext_vector_type(8))) short short8;
typedef __attribute__((ext_vector_type(4))) short short4v;
typedef __attribute__((ext_vector_type(4))) float floatx4;

__device__ __forceinline__ u16 f2bf(float f) {   // RTNE, finite inputs
    unsigned u = __float_as_uint(f);
    return (u16)((u + 0x7FFF + ((u >> 16) & 1)) >> 16);
}
__device__ __forceinline__ float bf2f(u16 b) {
    return __uint_as_float(((unsigned)b) << 16);
}
__device__ __forceinline__ int tri_start(int i) {  // quad-region offset of row i
    return (i * (129 - i)) >> 1;                   // i*64 - i*(i-1)/2
}

// ---- prep: packed weights row h -> dense bf16 [64][LSTR] + fp32 wlin ----
__global__ __launch_bounds__(256) void qvf_prep(
    const float* __restrict__ weights, u16* __restrict__ wdense,
    float* __restrict__ lwdense)
{
    __shared__ u16 W16[DOBS * LSTR];
    const int h = blockIdx.x;
    const float* __restrict__ wsrc = weights + h * WROW;

    // coalesced triangle read (verified R7 path)
    float wq[8];
#pragma unroll
    for (int p = 0; p < 8; ++p)
        wq[p] = wsrc[DOBS + p * 256 + threadIdx.x];          // 2048 elems
    float wq8 = 0.f;
    if (threadIdx.x < NQUAD - 2048)                          // last 32
        wq8 = wsrc[DOBS + 2048 + threadIdx.x];

    if (threadIdx.x < DOBS)
        lwdense[h * DOBS + threadIdx.x] = wsrc[threadIdx.x]; // wlin fp32

    {   // zero W16 (below-diagonal + pad); 4608 shorts = 576 short8 slots
        const short8 z = (short8)0;
        *(short8*)&W16[threadIdx.x * 8]         = z;
        *(short8*)&W16[(256 + threadIdx.x) * 8] = z;
        if (threadIdx.x < 64) *(short8*)&W16[(512 + threadIdx.x) * 8] = z;
    }
    __syncthreads();

    // scatter: linear q -> i = floor((129 - sqrt(129^2 - 8q))/2), j = i+q-S(i)
#pragma unroll
    for (int p = 0; p < 9; ++p) {
        const int q = p * 256 + threadIdx.x;
        if (p == 8 && q >= NQUAD) break;
        const float v = (p < 8) ? wq[p] : wq8;
        const int   t = 16641 - 8 * q;                 // exact in fp32 range
        int i = (int)((129.0f - __builtin_sqrtf((float)t)) * 0.5f);
        i = (i < 0) ? 0 : ((i > 63) ? 63 : i);
        if (q < tri_start(i)) --i;                     // +/-1 fixup
        if (q >= tri_start(i + 1)) ++i;
        const int j = i + (q - tri_start(i));
        W16[i * LSTR + j] = f2bf(v);
    }
    __syncthreads();

    // coalesced LDS -> global (9216 B per h)
    u16* __restrict__ dst = wdense + h * (DOBS * LSTR);
    *(short8*)&dst[threadIdx.x * 8]         = *(const short8*)&W16[threadIdx.x * 8];
    *(short8*)&dst[(256 + threadIdx.x) * 8] = *(const short8*)&W16[(256 + threadIdx.x) * 8];
    if (threadIdx.x < 64)
        *(short8*)&dst[(512 + threadIdx.x) * 8] = *(const short8*)&W16[(512 + threadIdx.x) * 8];
}

// ---- main: stage O + dense W, one barrier, MFMA, epilogue ----
__global__ __launch_bounds__(256) void qvf_main(
    const float* __restrict__ obs, const u16* __restrict__ wdense,
    const float* __restrict__ lwdense, const float* __restrict__ biases,
    float* __restrict__ out)
{
    __shared__ u16 O16[DOBS * LSTR];   // o tile [n_local][k] bf16
    __shared__ u16 W16[DOBS * LSTR];   // Wq     [i][k]       bf16
    __shared__ float LW[DOBS];         // wlin   fp32

    const int h    = blockIdx.x & (NH - 1);
    const int tidx = blockIdx.x >> 6;
    const int lane = threadIdx.x & 63;
    const int wv   = threadIdx.x >> 6;
    const int n0   = tidx * 64;

    // issue obs loads first (HBM latency), then dense-W (L2/L3-hot)
    const float* __restrict__ src = obs + ((size_t)n0 * NH + h) * DOBS;
    floatx4 ov[4];
#pragma unroll
    for (int p = 0; p < 4; ++p) {
        const int g  = p * 256 + threadIdx.x;
        const int r  = g >> 4;            // local path row 0..63
        const int c4 = g & 15;            // float4 within row
        ov[p] = *(const floatx4*)(src + (size_t)r * (NH * DOBS) + c4 * 4);
    }
    const u16* __restrict__ wsrc = wdense + h * (DOBS * LSTR);
    const short8 w0 = *(const short8*)(wsrc + threadIdx.x * 8);
    const short8 w1 = *(const short8*)(wsrc + (256 + threadIdx.x) * 8);
    short8 w2 = (short8)0;
    if (threadIdx.x < 64) w2 = *(const short8*)(wsrc + (512 + threadIdx.x) * 8);
    if (threadIdx.x < DOBS) LW[threadIdx.x] = lwdense[h * DOBS + threadIdx.x];

    // LDS stores
    *(short8*)&W16[threadIdx.x * 8]         = w0;
    *(short8*)&W16[(256 + threadIdx.x) * 8] = w1;
    if (threadIdx.x < 64) *(short8*)&W16[(512 + threadIdx.x) * 8] = w2;
#pragma unroll
    for (int p = 0; p < 4; ++p) {
        const int g  = p * 256 + threadIdx.x;
        const int r  = g >> 4;
        const int c4 = g & 15;
        short4v sv;
        sv[0] = (short)f2bf(ov[p].x); sv[1] = (short)f2bf(ov[p].y);
        sv[2] = (short)f2bf(ov[p].z); sv[3] = (short)f2bf(ov[p].w);
        *(short4v*)&O16[r * LSTR + c4 * 4] = sv;
    }
    __syncthreads();

    // ---- MFMA: C[m=n_local][i], acc seeded with fp32 wlin[i] ----
    const int col = lane & 15;
    const int qq  = lane >> 4;
    floatx4 acc[4];
#pragma unroll
    for (int ct = 0; ct < 4; ++ct) {
        const float wl = LW[ct * 16 + col];
        acc[ct][0] = wl; acc[ct][1] = wl; acc[ct][2] = wl; acc[ct][3] = wl;
    }

    const int mrow = wv * 16 + col;
#pragma unroll
    for (int ks = 0; ks < 2; ++ks) {
        const short8 a = *(const short8*)&O16[mrow * LSTR + ks * 32 + qq * 8];
#pragma unroll
        for (int ct = 0; ct < 4; ++ct) {
            const int i = ct * 16 + col;
            const short8 b = *(const short8*)&W16[i * LSTR + ks * 32 + qq * 8];
            acc[ct] = __builtin_amdgcn_mfma_f32_16x16x32_bf16(a, b, acc[ct], 0, 0, 0);
        }
    }

    // ---- epilogue: out[n] = sum_i o[n,i]*U[n,i] + bias ----
    // C/D layout: col = lane&15 (i), row = qq*4 + reg (n within 16-strip)
    float P[4] = {0.f, 0.f, 0.f, 0.f};
#pragma unroll
    for (int ct = 0; ct < 4; ++ct) {
#pragma unroll
        for (int r = 0; r < 4; ++r) {
            const int row = wv * 16 + qq * 4 + r;
            const u16 ovl = O16[row * LSTR + ct * 16 + col];
            P[r] = fmaf(acc[ct][r], bf2f(ovl), P[r]);
        }
    }
#pragma unroll
    for (int msk = 1; msk < 16; msk <<= 1) {
#pragma unroll
        for (int r = 0; r < 4; ++r) P[r] += __shfl_xor(P[r], msk, 64);
    }
    if (col == 0) {
        const float b = biases[h];
#pragma unroll
        for (int r = 0; r < 4; ++r) {
            const int row = wv * 16 + qq * 4 + r;
            out[(size_t)(n0 + row) * NH + h] = P[r] + b;
        }
    }
}

extern "C" void kernel_launch(void* const* d_in, const int* in_sizes, int n_in,
                              void* d_out, int out_size, void* d_ws, size_t ws_size,
                              hipStream_t stream) {
    const float* obs     = (const float*)d_in[0];
    const float* weights = (const float*)d_in[1];
    const float* biases  = (const float*)d_in[2];
    float* out           = (float*)d_out;

    u16*   wdense  = (u16*)d_ws;                                   // 64*4608 bf16 = 589824 B
    float* lwdense = (float*)((char*)d_ws + (size_t)NH * DOBS * LSTR * sizeof(u16)); // +16 KB

    const int N = in_sizes[0] / (NH * DOBS);   // 1024

    qvf_prep<<<dim3(NH), dim3(256), 0, stream>>>(weights, wdense, lwdense);
    qvf_main<<<dim3((N / 64) * NH), dim3(256), 0, stream>>>(obs, wdense, lwdense, biases, out);
}

// Round 2
// 68.885 us; speedup vs baseline: 1.0173x; 1.0173x over previous
//
#include <hip/hip_runtime.h>

// QuadraticTimeVaryingVF via MFMA, single fused kernel (R9).
// out[n,h] = b[h] + sum_i o_i*(wlin[h,i] + sum_{j>=i} wq[h,i,j]*o_j)
//
// R8 post-mortem: prep+main split REGRESSED (+1.7us). The R7 front-end
// (scattered wq loads + sqrt scatter + zeroing) was already hidden under
// the obs HBM latency; splitting it out added a serialized launch.
// R9 = single kernel again, with the only changes that shorten the
// CRITICAL PATH rather than the hidden work:
//   (1) ONE barrier instead of two: zero W16 strictly below the diagonal
//       (j < i), which is address-disjoint from the scatter (j >= i), so
//       zeros and scatter need no ordering; pad cols 64..71 are never
//       read by MFMA (k < 64) and are not written at all.
//   (2) obs global loads issued into registers first (HBM latency leads).
// Arithmetic bit-identical to R7/R8.

#define DOBS 64
#define NH   64
#define WROW 2145
#define NQUAD 2080            // upper-tri count
#define LSTR 72               // LDS row stride (bf16): 144 B, 16B-aligned
                              // (b128 reads at LSTR=72 are conflict-free)

typedef unsigned short u16;
typedef __attribute__((ext_vector_type(8))) short short8;
typedef __attribute__((ext_vector_type(4))) short short4v;
typedef __attribute__((ext_vector_type(4))) float floatx4;

__device__ __forceinline__ u16 f2bf(float f) {   // RTNE, finite inputs
    unsigned u = __float_as_uint(f);
    return (u16)((u + 0x7FFF + ((u >> 16) & 1)) >> 16);
}
__device__ __forceinline__ float bf2f(u16 b) {
    return __uint_as_float(((unsigned)b) << 16);
}
__device__ __forceinline__ int tri_start(int i) {  // quad-region offset of row i
    return (i * (129 - i)) >> 1;                   // i*64 - i*(i-1)/2
}

__global__ __launch_bounds__(256) void qvf_main(
    const float* __restrict__ obs, const float* __restrict__ weights,
    const float* __restrict__ biases, float* __restrict__ out, int N)
{
    __shared__ u16 O16[DOBS * LSTR];   // o tile   [n_local][k] bf16
    __shared__ u16 W16[DOBS * LSTR];   // Wq       [i][k]       bf16
    __shared__ float LW[DOBS];         // wlin     fp32

    const int h    = blockIdx.x & (NH - 1);
    const int tidx = blockIdx.x >> 6;
    const int lane = threadIdx.x & 63;
    const int wv   = threadIdx.x >> 6;
    const int n0   = tidx * 64;

    // ---- issue obs loads first (HBM, longest latency) ----
    const float* __restrict__ src = obs + ((size_t)n0 * NH + h) * DOBS;
    floatx4 ov[4];
#pragma unroll
    for (int p = 0; p < 4; ++p) {
        const int g  = p * 256 + threadIdx.x;
        const int r  = g >> 4;            // local path row 0..63
        const int c4 = g & 15;            // float4 within row
        ov[p] = *(const floatx4*)(src + (size_t)r * (NH * DOBS) + c4 * 4);
    }

    // ---- coalesced quad-weight loads (L2/L3-hot after first blocks) ----
    const float* __restrict__ wsrc = weights + h * WROW;
    float wq[8];
#pragma unroll
    for (int p = 0; p < 8; ++p)
        wq[p] = wsrc[DOBS + p * 256 + threadIdx.x];          // 2048 elems
    float wq8 = 0.f;
    if (threadIdx.x < NQUAD - 2048)                          // last 32
        wq8 = wsrc[DOBS + 2048 + threadIdx.x];

    // linear weights -> LDS fp32
    if (threadIdx.x < DOBS) LW[threadIdx.x] = wsrc[threadIdx.x];

    // ---- masked zero: strictly-below-diagonal of W16 (one row/thread) ----
    // Disjoint (at u16 granularity) from every scatter target (j >= i),
    // so NO barrier is needed between zeroing and scatter.
    if (threadIdx.x < DOBS) {
        const int i     = threadIdx.x;
        const int nfull = i >> 3;                  // full short8 slots < diag
        const short8 z  = (short8)0;
        for (int k = 0; k < nfull; ++k)
            *(short8*)&W16[i * LSTR + k * 8] = z;
        for (int j = nfull * 8; j < i; ++j)        // boundary slot, j < i only
            W16[i * LSTR + j] = 0;
    }

    // ---- scatter quad weights into W16 upper-tri ----
    // linear q -> i = floor((129 - sqrt(129^2 - 8q))/2), j = i + q - S(i)
#pragma unroll
    for (int p = 0; p < 9; ++p) {
        const int q = p * 256 + threadIdx.x;
        if (p == 8 && q >= NQUAD) break;
        const float v = (p < 8) ? wq[p] : wq8;
        const int   t = 16641 - 8 * q;                 // exact in fp32 range
        int i = (int)((129.0f - __builtin_sqrtf((float)t)) * 0.5f);
        i = (i < 0) ? 0 : ((i > 63) ? 63 : i);
        if (q < tri_start(i)) --i;                     // +/-1 fixup
        if (q >= tri_start(i + 1)) ++i;
        const int j = i + (q - tri_start(i));
        W16[i * LSTR + j] = f2bf(v);
    }

    // ---- obs regs -> bf16 LDS ----
#pragma unroll
    for (int p = 0; p < 4; ++p) {
        const int g  = p * 256 + threadIdx.x;
        const int r  = g >> 4;
        const int c4 = g & 15;
        short4v sv;
        sv[0] = (short)f2bf(ov[p].x); sv[1] = (short)f2bf(ov[p].y);
        sv[2] = (short)f2bf(ov[p].z); sv[3] = (short)f2bf(ov[p].w);
        *(short4v*)&O16[r * LSTR + c4 * 4] = sv;
    }
    __syncthreads();   // the ONLY barrier

    // ---- MFMA: C[m=n_local][i], acc seeded with fp32 wlin[i] ----
    const int col = lane & 15;
    const int qq  = lane >> 4;
    floatx4 acc[4];
#pragma unroll
    for (int ct = 0; ct < 4; ++ct) {
        const float wl = LW[ct * 16 + col];
        acc[ct][0] = wl; acc[ct][1] = wl; acc[ct][2] = wl; acc[ct][3] = wl;
    }

    const int mrow = wv * 16 + col;
#pragma unroll
    for (int ks = 0; ks < 2; ++ks) {
        const short8 a = *(const short8*)&O16[mrow * LSTR + ks * 32 + qq * 8];
#pragma unroll
        for (int ct = 0; ct < 4; ++ct) {
            const int i = ct * 16 + col;
            const short8 b = *(const short8*)&W16[i * LSTR + ks * 32 + qq * 8];
            acc[ct] = __builtin_amdgcn_mfma_f32_16x16x32_bf16(a, b, acc[ct], 0, 0, 0);
        }
    }

    // ---- epilogue: out[n] = sum_i o[n,i]*U[n,i] + bias ----
    // C/D layout: col = lane&15 (i), row = qq*4 + reg (n within 16-strip)
    float P[4] = {0.f, 0.f, 0.f, 0.f};
#pragma unroll
    for (int ct = 0; ct < 4; ++ct) {
#pragma unroll
        for (int r = 0; r < 4; ++r) {
            const int row = wv * 16 + qq * 4 + r;
            const u16 ovl = O16[row * LSTR + ct * 16 + col];
            P[r] = fmaf(acc[ct][r], bf2f(ovl), P[r]);
        }
    }
#pragma unroll
    for (int msk = 1; msk < 16; msk <<= 1) {
#pragma unroll
        for (int r = 0; r < 4; ++r) P[r] += __shfl_xor(P[r], msk, 64);
    }
    if (col == 0) {
        const float b = biases[h];
#pragma unroll
        for (int r = 0; r < 4; ++r) {
            const int row = wv * 16 + qq * 4 + r;
            out[(size_t)(n0 + row) * NH + h] = P[r] + b;
        }
    }
}

extern "C" void kernel_launch(void* const* d_in, const int* in_sizes, int n_in,
                              void* d_out, int out_size, void* d_ws, size_t ws_size,
                              hipStream_t stream) {
    const float* obs     = (const float*)d_in[0];
    const float* weights = (const float*)d_in[1];
    const float* biases  = (const float*)d_in[2];
    float* out           = (float*)d_out;

    const int N = in_sizes[0] / (NH * DOBS);   // 1024
    qvf_main<<<dim3((N / 64) * NH), dim3(256), 0, stream>>>(obs, weights, biases, out, N);
}